// Round 7
// baseline (736.575 us; speedup 1.0000x reference)
//
#include <hip/hip_runtime.h>
#include <hip/hip_fp16.h>

constexpr int IN_DIM  = 256;
constexpr int HID_DIM = 128;
constexpr int OUT_DIM = 64;

constexpr int NPB_SHIFT = 8;          // 256 nodes per bucket
constexpr int NPB   = 1 << NPB_SHIFT;
constexpr int NBMAX = 512;            // max buckets supported in LDS tables
constexpr int CHUNK = 4096;           // edges per binning block
constexpr int CAP_B = 12288;          // LDS col-stage capacity (48 KB)

typedef _Float16 half8 __attribute__((ext_vector_type(8)));
typedef float floatx4 __attribute__((ext_vector_type(4)));

// ---------------- CSR build via bucketed counting sort ----------------

__global__ __launch_bounds__(256) void k_hist(const int* __restrict__ dst, int E, int NB,
                                              int* __restrict__ bsize) {
  __shared__ int h[NBMAX];
  for (int i = threadIdx.x; i < NB; i += 256) h[i] = 0;
  __syncthreads();
  int e0 = blockIdx.x * CHUNK;
  int e1 = min(e0 + CHUNK, E);
  for (int e = e0 + threadIdx.x; e < e1; e += 256) {
    int d = __builtin_nontemporal_load(&dst[e]);
    atomicAdd(&h[d >> NPB_SHIFT], 1);
  }
  __syncthreads();
  for (int b = threadIdx.x; b < NB; b += 256) {
    int c = h[b];
    if (c) atomicAdd(&bsize[b], c);
  }
}

__global__ __launch_bounds__(512) void k_scanb(const int* __restrict__ bsize, int NB, int E,
                                               int* __restrict__ boff, int* __restrict__ gcur) {
  __shared__ int sh[NBMAX + 1];
  for (int i = threadIdx.x; i < NB; i += 512) sh[i] = bsize[i];
  __syncthreads();
  if (threadIdx.x == 0) {
    int run = 0;
    for (int b = 0; b < NB; b++) { int v = sh[b]; sh[b] = run; run += v; }
    sh[NB] = run;
  }
  __syncthreads();
  for (int i = threadIdx.x; i < NB; i += 512) { boff[i] = sh[i]; gcur[i] = sh[i]; }
  if (threadIdx.x == 0) boff[NB] = sh[NB];
}

// bin entry: 4 bytes = (dst&255)<<24 | src  (src < 2^24; bucket from position)
__global__ __launch_bounds__(256) void k_binA(const int* __restrict__ src,
                                              const int* __restrict__ dst, int E, int NB,
                                              int* __restrict__ gcur,
                                              unsigned int* __restrict__ bin) {
  __shared__ unsigned int sbuf[CHUNK];      // 16 KB
  __shared__ unsigned short sbb[CHUNK];     // 8 KB (bucket per staged entry)
  __shared__ int h[NBMAX], lofs[NBMAX], wofs[NBMAX], hcur[NBMAX];
  for (int i = threadIdx.x; i < NB; i += 256) h[i] = 0;
  __syncthreads();
  int e0 = blockIdx.x * CHUNK;
  int e1 = min(e0 + CHUNK, E);
  for (int e = e0 + threadIdx.x; e < e1; e += 256) {
    int d = __builtin_nontemporal_load(&dst[e]);
    atomicAdd(&h[d >> NPB_SHIFT], 1);
  }
  __syncthreads();
  for (int b = threadIdx.x; b < NB; b += 256) {
    int c = h[b];
    if (c) wofs[b] = atomicAdd(&gcur[b], c);
  }
  if (threadIdx.x == 0) {
    int run = 0;
    for (int b = 0; b < NB; b++) { lofs[b] = run; run += h[b]; }
  }
  __syncthreads();
  for (int b = threadIdx.x; b < NB; b += 256) hcur[b] = lofs[b];
  __syncthreads();
  for (int e = e0 + threadIdx.x; e < e1; e += 256) {
    int d = dst[e];
    int s = src[e];
    int b = d >> NPB_SHIFT;
    int p = atomicAdd(&hcur[b], 1);
    sbuf[p] = ((unsigned int)(d & (NPB - 1)) << 24) | (unsigned int)s;
    sbb[p] = (unsigned short)b;
  }
  __syncthreads();
  int total = e1 - e0;
  for (int i = threadIdx.x; i < total; i += 256) {
    int b = sbb[i];
    bin[(size_t)wofs[b] + (i - lofs[b])] = sbuf[i];
  }
}

__global__ __launch_bounds__(256) void k_passB(const unsigned int* __restrict__ bin,
                                               const int* __restrict__ boff, int NB, int N, int E,
                                               int* __restrict__ rowptr, float* __restrict__ dis,
                                               int* __restrict__ col) {
  __shared__ unsigned int colbuf[CAP_B];  // 48 KB
  __shared__ int lcnt[NPB], lofs2[NPB + 1], lpos[NPB];
  int b = blockIdx.x;
  int lo = b << NPB_SHIFT;
  int e0 = boff[b], e1 = boff[b + 1];
  int tot = e1 - e0;
  if (threadIdx.x < NPB) lcnt[threadIdx.x] = 0;
  __syncthreads();
  for (int i = threadIdx.x; i < tot; i += 256) {
    unsigned int v = bin[(size_t)e0 + i];
    atomicAdd(&lcnt[v >> 24], 1);
  }
  __syncthreads();
  if (threadIdx.x == 0) {
    int run = 0;
    for (int i = 0; i < NPB; i++) { lofs2[i] = run; run += lcnt[i]; }
    lofs2[NPB] = run;
  }
  __syncthreads();
  if (threadIdx.x < NPB) {
    int node = lo + threadIdx.x;
    if (node < N) {
      rowptr[node] = e0 + lofs2[threadIdx.x];
      dis[node] = rsqrtf((float)lcnt[threadIdx.x] + 1.0f);  // +1 self loop
    }
    lpos[threadIdx.x] = lofs2[threadIdx.x];
  }
  __syncthreads();
  for (int i = threadIdx.x; i < tot; i += 256) {
    unsigned int v = bin[(size_t)e0 + i];
    int idx = v >> 24;
    int p = atomicAdd(&lpos[idx], 1);
    unsigned int s = v & 0x00FFFFFFu;
    if (p < CAP_B) colbuf[p] = s;
    else col[(size_t)e0 + p] = (int)s;
  }
  __syncthreads();
  int cp = min(tot, CAP_B);
  for (int i = threadIdx.x; i < cp; i += 256)
    __builtin_nontemporal_store(colbuf[i], (unsigned int*)&col[(size_t)e0 + i]);
  if (b == 0 && threadIdx.x == 0) rowptr[N] = E;
}

// ---------------- W pre-pack into MFMA B-fragment order (fp16) ----------------
// B-frag for 16x16x32_f16: lane holds B[k = (lane>>4)*8 + j][n = lane&15].
// Wp flat index: ((ct*(K/32) + ks)*64 + lane)*8 + j, ct = n>>4, ks = k>>5.

template <int K, int N>
__device__ inline void packW_one(const float* __restrict__ W, _Float16* __restrict__ Wp,
                                 int idx) {
  int k = idx / N, n = idx % N;
  int ct = n >> 4, ks = k >> 5, q = (k >> 3) & 3, j = k & 7;
  int lane = (n & 15) + (q << 4);
  Wp[((((size_t)ct * (K / 32) + ks) * 64 + lane) << 3) + j] = (_Float16)W[idx];
}

__global__ __launch_bounds__(256) void k_packAll(const float* __restrict__ W1, _Float16* __restrict__ Wp1,
                                                 const float* __restrict__ W2, _Float16* __restrict__ Wp2,
                                                 const float* __restrict__ W3, _Float16* __restrict__ Wp3) {
  constexpr int S1 = IN_DIM * HID_DIM;            // 32768
  constexpr int S2 = S1 + HID_DIM * HID_DIM;      // 49152
  constexpr int S3 = S2 + HID_DIM * OUT_DIM;      // 57344
  int idx = blockIdx.x * 256 + threadIdx.x;
  if (idx < S1) packW_one<IN_DIM, HID_DIM>(W1, Wp1, idx);
  else if (idx < S2) packW_one<HID_DIM, HID_DIM>(W2, Wp2, idx - S1);
  else if (idx < S3) packW_one<HID_DIM, OUT_DIM>(W3, Wp3, idx - S2);
}

// ---------------- MFMA GEMM: out[r][c] = fp16(dis[r] * sum_k A[r][k]*W[k][c]) --------
// r6 restructure (old form was latency-bound: MfmaUtil 3.9%, everything idle, 61 us):
// 8-wave blocks stage the FULL packed W once (64/32/16 KB), ONE barrier, then a
// barrier-free grid-stride loop over 128-row tiles. Grid = 512 (2 blocks/CU at
// launch_bounds(512,4)). Kills the stage-barrier-compute lockstep and cuts W-stage
// L2 traffic 1563*64KB=100MB -> 512*WKB; A-load latency hides across 16 waves/CU.

template <int K, int N, typename AT>
__global__ __launch_bounds__(512, 4) void k_gemm_mfma(const AT* __restrict__ A,
                                                      const _Float16* __restrict__ Wp,
                                                      const float* __restrict__ dis,
                                                      __half* __restrict__ out, int M,
                                                      int ntiles) {
  constexpr int CT = N / 16;   // 16-col tiles
  constexpr int KS = K / 32;   // 32-k steps
  constexpr int NF4 = CT * KS * 64;   // full W in float4 units (<=4096 = 64 KB)
  __shared__ float4 wlds[NF4];

  const int wave = threadIdx.x >> 6, lane = threadIdx.x & 63;
  const int q = lane >> 4, mlane = lane & 15;

  // stage full W once per block
  for (int i = threadIdx.x; i < NF4; i += 512)
    wlds[i] = ((const float4*)Wp)[i];
  __syncthreads();

  for (int t = blockIdx.x; t < ntiles; t += gridDim.x) {
    const int row0 = t * 128 + wave * 16;
    int arow = row0 + mlane;
    if (arow > M - 1) arow = M - 1;  // clamp (dup row, stores guarded)

    floatx4 acc[CT];
#pragma unroll
    for (int c = 0; c < CT; c++) acc[c] = (floatx4){0.f, 0.f, 0.f, 0.f};

#pragma unroll
    for (int ks = 0; ks < KS; ks++) {
      half8 a;
      if constexpr (sizeof(AT) == 4) {
        const float* ap = &A[(size_t)arow * K + ks * 32 + q * 8];
        float4 f0 = *(const float4*)ap;
        float4 f1 = *(const float4*)(ap + 4);
        a[0] = (_Float16)f0.x; a[1] = (_Float16)f0.y;
        a[2] = (_Float16)f0.z; a[3] = (_Float16)f0.w;
        a[4] = (_Float16)f1.x; a[5] = (_Float16)f1.y;
        a[6] = (_Float16)f1.z; a[7] = (_Float16)f1.w;
      } else {
        a = *(const half8*)&A[(size_t)arow * K + ks * 32 + q * 8];
      }
#pragma unroll
      for (int c = 0; c < CT; c++) {
        half8 b = *(const half8*)&wlds[(c * KS + ks) * 64 + lane];
        acc[c] = __builtin_amdgcn_mfma_f32_16x16x32_f16(a, b, acc[c], 0, 0, 0);
      }
    }

    // C/D layout: col = lane&15 (+ct*16), row = q*4 + r
    float dv[4]; int orow[4];
#pragma unroll
    for (int r = 0; r < 4; r++) {
      orow[r] = row0 + q * 4 + r;
      dv[r] = (orow[r] < M) ? dis[orow[r]] : 0.f;
    }
#pragma unroll
    for (int c = 0; c < CT; c++) {
      int cl = c * 16 + mlane;
#pragma unroll
      for (int r = 0; r < 4; r++)
        if (orow[r] < M)
          out[(size_t)orow[r] * N + cl] = __float2half_rn(dv[r] * acc[c][r]);
    }
  }
}

// ---------------- aggregation F=128, quad-gather + shfl-distributed col ----------------
// One wave per node; lane = (r = lane>>4 neighbor-in-quad, c = lane&15 16B chunk).
// Col indices: ONE 64-wide VMEM load per 64 neighbors, __shfl distributes (LDS pipe).
// Split into two half-node dispatches so rocprof top-5 surfaces next-tier kernels.

template <bool RELU>
__global__ __launch_bounds__(256) void k_agg128(const __half* __restrict__ g,
                                                const int* __restrict__ rowptr,
                                                const int* __restrict__ col,
                                                const float* __restrict__ dis,
                                                const float* __restrict__ bias,
                                                __half* __restrict__ out, int n, int v0) {
  const int lane = threadIdx.x & 63;
  const int r = lane >> 4;          // 0..3
  const int c = lane & 15;          // 0..15
  const int v = v0 + blockIdx.x * 4 + (threadIdx.x >> 6);
  if (v >= n) return;
  int p = rowptr[v], end = rowptr[v + 1];
  const float dv = dis[v];

  float acc[8];
#pragma unroll
  for (int i = 0; i < 8; i++) acc[i] = 0.f;
  if (r == 0) {  // self term, counted once
    half8 s = *(const half8*)&g[(size_t)v * 128 + c * 8];
#pragma unroll
    for (int i = 0; i < 8; i++) acc[i] += (float)s[i];
  }

  while (p < end) {
    int navail = end - p;
    if (navail > 64) navail = 64;
    int cv = __builtin_nontemporal_load(&col[p + (lane < navail ? lane : 0)]);
    int done = 0;
    while (navail - done >= 8) {  // two quad-gathers in flight
      int u0 = __shfl(cv, done + r);
      int u1 = __shfl(cv, done + 4 + r);
      half8 t0 = *(const half8*)&g[(size_t)u0 * 128 + c * 8];
      half8 t1 = *(const half8*)&g[(size_t)u1 * 128 + c * 8];
#pragma unroll
      for (int i = 0; i < 8; i++) acc[i] += (float)t0[i];
#pragma unroll
      for (int i = 0; i < 8; i++) acc[i] += (float)t1[i];
      done += 8;
    }
    int remn = navail - done;  // 0..7
    if (remn > 0) {
      int m0 = remn < 4 ? remn : 4;
      int u0 = __shfl(cv, done + (r < m0 ? r : 0));
      half8 t0 = *(const half8*)&g[(size_t)u0 * 128 + c * 8];
      float k0 = (r < m0) ? 1.f : 0.f;
#pragma unroll
      for (int i = 0; i < 8; i++) acc[i] = fmaf(k0, (float)t0[i], acc[i]);
      if (remn > 4) {
        int m1 = remn - 4;
        int u1 = __shfl(cv, done + 4 + (r < m1 ? r : 0));
        half8 t1 = *(const half8*)&g[(size_t)u1 * 128 + c * 8];
        float k1 = (r < m1) ? 1.f : 0.f;
#pragma unroll
        for (int i = 0; i < 8; i++) acc[i] = fmaf(k1, (float)t1[i], acc[i]);
      }
    }
    p += navail;
  }

  // merge the 4 row-groups (lanes c, c+16, c+32, c+48)
#pragma unroll
  for (int i = 0; i < 8; i++) {
    acc[i] += __shfl_xor(acc[i], 16);
    acc[i] += __shfl_xor(acc[i], 32);
  }

  if (r == 0) {
    half8 h;
#pragma unroll
    for (int i = 0; i < 8; i++) {
      float o = fmaf(dv, acc[i], bias[c * 8 + i]);
      if (RELU) o = fmaxf(o, 0.f);
      h[i] = (_Float16)o;
    }
    *(half8*)&out[(size_t)v * 128 + c * 8] = h;
  }
}

// ---------------- aggregation F=64, oct-gather + shfl-distributed col ----------------

__global__ __launch_bounds__(256) void k_agg64(const __half* __restrict__ g,
                                               const int* __restrict__ rowptr,
                                               const int* __restrict__ col,
                                               const float* __restrict__ dis,
                                               const float* __restrict__ bias,
                                               float* __restrict__ out, int n) {
  const int lane = threadIdx.x & 63;
  const int r = lane >> 3;          // 0..7
  const int c = lane & 7;           // 0..7
  const int v = blockIdx.x * 4 + (threadIdx.x >> 6);
  if (v >= n) return;
  int p = rowptr[v], end = rowptr[v + 1];
  const float dv = dis[v];

  float acc[8];
#pragma unroll
  for (int i = 0; i < 8; i++) acc[i] = 0.f;
  if (r == 0) {
    half8 s = *(const half8*)&g[(size_t)v * 64 + c * 8];
#pragma unroll
    for (int i = 0; i < 8; i++) acc[i] += (float)s[i];
  }

  while (p < end) {
    int navail = end - p;
    if (navail > 64) navail = 64;
    int cv = __builtin_nontemporal_load(&col[p + (lane < navail ? lane : 0)]);
    int done = 0;
    while (navail - done >= 16) {  // two oct-gathers in flight
      int u0 = __shfl(cv, done + r);
      int u1 = __shfl(cv, done + 8 + r);
      half8 t0 = *(const half8*)&g[(size_t)u0 * 64 + c * 8];
      half8 t1 = *(const half8*)&g[(size_t)u1 * 64 + c * 8];
#pragma unroll
      for (int i = 0; i < 8; i++) acc[i] += (float)t0[i];
#pragma unroll
      for (int i = 0; i < 8; i++) acc[i] += (float)t1[i];
      done += 16;
    }
    int remn = navail - done;  // 0..15
    if (remn > 0) {
      int m0 = remn < 8 ? remn : 8;
      int u0 = __shfl(cv, done + (r < m0 ? r : 0));
      half8 t0 = *(const half8*)&g[(size_t)u0 * 64 + c * 8];
      float k0 = (r < m0) ? 1.f : 0.f;
#pragma unroll
      for (int i = 0; i < 8; i++) acc[i] = fmaf(k0, (float)t0[i], acc[i]);
      if (remn > 8) {
        int m1 = remn - 8;
        int u1 = __shfl(cv, done + 8 + (r < m1 ? r : 0));
        half8 t1 = *(const half8*)&g[(size_t)u1 * 64 + c * 8];
        float k1 = (r < m1) ? 1.f : 0.f;
#pragma unroll
        for (int i = 0; i < 8; i++) acc[i] = fmaf(k1, (float)t1[i], acc[i]);
      }
    }
    p += navail;
  }

  // merge the 8 row-groups (lanes differing in bits 3..5)
#pragma unroll
  for (int i = 0; i < 8; i++) {
    acc[i] += __shfl_xor(acc[i], 8);
    acc[i] += __shfl_xor(acc[i], 16);
    acc[i] += __shfl_xor(acc[i], 32);
  }

  if (r == 0) {
    float4 o0, o1;
    float ov[8];
#pragma unroll
    for (int i = 0; i < 8; i++) ov[i] = fmaf(dv, acc[i], bias[c * 8 + i]);
    o0.x = ov[0]; o0.y = ov[1]; o0.z = ov[2]; o0.w = ov[3];
    o1.x = ov[4]; o1.y = ov[5]; o1.z = ov[6]; o1.w = ov[7];
    *(float4*)&out[(size_t)v * 64 + c * 8]     = o0;
    *(float4*)&out[(size_t)v * 64 + c * 8 + 4] = o1;
  }
}

// ---------------- launch ----------------

extern "C" void kernel_launch(void* const* d_in, const int* in_sizes, int n_in,
                              void* d_out, int out_size, void* d_ws, size_t ws_size,
                              hipStream_t stream) {
  const float* x  = (const float*)d_in[0];
  const int*   ei = (const int*)d_in[1];
  const float* W1 = (const float*)d_in[2];
  const float* b1 = (const float*)d_in[3];
  const float* W2 = (const float*)d_in[4];
  const float* b2 = (const float*)d_in[5];
  const float* W3 = (const float*)d_in[6];
  const float* b3 = (const float*)d_in[7];
  float* outp = (float*)d_out;

  const int N = in_sizes[0] / IN_DIM;   // 100000
  const int E = in_sizes[1] / 2;        // 3200000
  const int* src = ei;
  const int* dst = ei + E;
  const int NB = (N + NPB - 1) >> NPB_SHIFT;  // 391 buckets

  char* w = (char*)d_ws;
  auto take = [&](size_t bytes) {
    char* r = w;
    w += (bytes + 255) & ~size_t(255);
    return r;
  };
  float*  dis    = (float*)take((size_t)N * 4);
  int*    rowptr = (int*)take((size_t)(N + 1) * 4);
  int*    bsize  = (int*)take((size_t)NB * 4);
  int*    boff   = (int*)take((size_t)(NB + 1) * 4);
  int*    gcur   = (int*)take((size_t)NB * 4);
  int*    col    = (int*)take((size_t)E * 4);
  unsigned int* bin = (unsigned int*)take((size_t)E * 4);
  _Float16* Wp1  = (_Float16*)take((size_t)IN_DIM * HID_DIM * 2);
  _Float16* Wp2  = (_Float16*)take((size_t)HID_DIM * HID_DIM * 2);
  _Float16* Wp3  = (_Float16*)take((size_t)HID_DIM * OUT_DIM * 2);
  __half* gbuf   = (__half*)take((size_t)N * 128 * 2);  // GEMM out / gather buffer
  __half* bufH   = (__half*)take((size_t)N * 128 * 2);  // agg out (next GEMM A)

  const int cb = (E + CHUNK - 1) / CHUNK;
  hipMemsetAsync(bsize, 0, (size_t)NB * 4, stream);
  hipLaunchKernelGGL(k_hist, dim3(cb), dim3(256), 0, stream, dst, E, NB, bsize);
  hipLaunchKernelGGL(k_scanb, dim3(1), dim3(512), 0, stream, bsize, NB, E, boff, gcur);
  hipLaunchKernelGGL(k_binA, dim3(cb), dim3(256), 0, stream, src, dst, E, NB, gcur, bin);
  hipLaunchKernelGGL(k_passB, dim3(NB), dim3(256), 0, stream, bin, boff, NB, N, E, rowptr, dis, col);

  hipLaunchKernelGGL(k_packAll, dim3((IN_DIM * HID_DIM + HID_DIM * HID_DIM + HID_DIM * OUT_DIM + 255) / 256),
                     dim3(256), 0, stream, W1, Wp1, W2, Wp2, W3, Wp3);

  const int ntiles = (N + 127) / 128;
  const int ggrid = ntiles < 512 ? ntiles : 512;   // 2 blocks/CU, one launch wave
  const int ab = (N + 3) / 4;
  const int nh = (N + 1) / 2;               // half-node split for agg128
  const int ab1 = (nh + 3) / 4;
  const int ab2 = (N - nh + 3) / 4;
  // layer 1: gbuf = fp16(dis*(x@W1)) -> agg+relu (two half dispatches) -> bufH
  hipLaunchKernelGGL((k_gemm_mfma<IN_DIM, HID_DIM, float>), dim3(ggrid), dim3(512), 0, stream, x, Wp1, dis, gbuf, N, ntiles);
  hipLaunchKernelGGL((k_agg128<true>), dim3(ab1), dim3(256), 0, stream, gbuf, rowptr, col, dis, b1, bufH, N, 0);
  hipLaunchKernelGGL((k_agg128<true>), dim3(ab2), dim3(256), 0, stream, gbuf, rowptr, col, dis, b1, bufH, N, nh);
  // layer 2
  hipLaunchKernelGGL((k_gemm_mfma<HID_DIM, HID_DIM, __half>), dim3(ggrid), dim3(512), 0, stream, bufH, Wp2, dis, gbuf, N, ntiles);
  hipLaunchKernelGGL((k_agg128<true>), dim3(ab1), dim3(256), 0, stream, gbuf, rowptr, col, dis, b2, bufH, N, 0);
  hipLaunchKernelGGL((k_agg128<true>), dim3(ab2), dim3(256), 0, stream, gbuf, rowptr, col, dis, b2, bufH, N, nh);
  // layer 3 (no relu), 64-dim, fp32 straight to d_out
  hipLaunchKernelGGL((k_gemm_mfma<HID_DIM, OUT_DIM, __half>), dim3(ggrid), dim3(512), 0, stream, bufH, Wp3, dis, gbuf, N, ntiles);
  hipLaunchKernelGGL(k_agg64, dim3(ab), dim3(256), 0, stream, gbuf, rowptr, col, dis, b3, outp, N);
}